// Round 6
// baseline (165.986 us; speedup 1.0000x reference)
//
#include <hip/hip_runtime.h>
#include <hip/hip_fp16.h>

#define Bn   8
#define CM_  64
#define CIN  128   // mem(64) + que(64)
#define CO_  64
#define Hn   128
#define Wn   128
#define Kn   9
#define COFF 27    // 18 offset + 9 mask channels
#define HW   (Hn * Wn)

typedef __attribute__((ext_vector_type(8))) _Float16 f16x8;  // 8 f16 = 4 VGPRs
typedef __attribute__((ext_vector_type(4))) float f32x4;

__device__ __forceinline__ unsigned h22u(__half2 h) {
    unsigned u; __builtin_memcpy(&u, &h, 4); return u;
}
__device__ __forceinline__ __half2 u2h2(unsigned u) {
    __half2 h; __builtin_memcpy(&h, &u, 4); return h;
}
__device__ __forceinline__ unsigned short f2h(float x) {
    __half h = __float2half(x);
    unsigned short u; __builtin_memcpy(&u, &h, 2); return u;
}

// ---------------------------------------------------------------------------
// Kernel T: transpose concat(mem,que) [b][c][px] fp32 -> xT[b][px][c] f16.
// ---------------------------------------------------------------------------
__global__ __launch_bounds__(256) void transpose_kernel(
    const float* __restrict__ mem, const float* __restrict__ que,
    uint4* __restrict__ xT4)
{
    __shared__ unsigned tile[64 * 65];

    const int bb   = blockIdx.x & 7;
    const int pix0 = (blockIdx.x >> 3) * 64;
    const int tid  = threadIdx.x;
    const int pxL  = tid & 63;
    const int cg   = tid >> 6;

    const float* mb = mem + (size_t)bb * CM_ * HW + pix0 + pxL;
    const float* qb = que + (size_t)bb * CM_ * HW + pix0 + pxL;

    #pragma unroll
    for (int i = 0; i < 16; ++i) {
        const int c = cg * 32 + 2 * i;
        const float v0 = (c < CM_) ? mb[(size_t)c * HW]       : qb[(size_t)(c - CM_) * HW];
        const float v1 = (c + 1 < CM_) ? mb[(size_t)(c + 1) * HW] : qb[(size_t)(c + 1 - CM_) * HW];
        tile[pxL * 65 + cg * 16 + i] = h22u(__floats2half2_rn(v0, v1));
    }
    __syncthreads();

    uint4* dst = xT4 + (size_t)(bb * HW + pix0) * 16;
    #pragma unroll
    for (int p = 0; p < 4; ++p) {
        const int G  = p * 256 + tid;
        const int px = G >> 4;
        const int u  = G & 15;
        uint4 v;
        v.x = tile[px * 65 + u * 4 + 0];
        v.y = tile[px * 65 + u * 4 + 1];
        v.z = tile[px * 65 + u * 4 + 2];
        v.w = tile[px * 65 + u * 4 + 3];
        dst[G] = v;
    }
}

// ---------------------------------------------------------------------------
// Kernel W: pack w_def AND w_off into MFMA A-fragment order (f16), one launch.
//   wpd: idx = (((g*9+k)*2+f)*64+L)*8+j  -> W[o=g*16+(L&15)][c=f*32+(L>>4)*8+j], tap k
//   wpo: idx = (((ot*9+tap)*4+s)*64+L)*8+j -> o=ot*16+(L&15) (pad 27->32), c=s*32+...
// ---------------------------------------------------------------------------
__global__ __launch_bounds__(256) void wprep_all_kernel(
    const float* __restrict__ w_def, const float* __restrict__ w_off,
    unsigned short* __restrict__ wpd, unsigned short* __restrict__ wpo)
{
    int idx = blockIdx.x * 256 + threadIdx.x;
    if (idx < CO_ * CM_ * Kn) {
        const int j  = idx & 7;
        const int L  = (idx >> 3) & 63;
        const int f  = (idx >> 9) & 1;
        const int gk = idx >> 10;
        const int k  = gk % 9;
        const int g  = gk / 9;
        const int o  = g * 16 + (L & 15);
        const int c  = f * 32 + (L >> 4) * 8 + j;
        wpd[idx] = f2h(w_def[(size_t)(o * CM_ + c) * Kn + k]);
        return;
    }
    idx -= CO_ * CM_ * Kn;
    if (idx < 2 * 9 * 4 * 64 * 8) {
        const int j   = idx & 7;
        const int L   = (idx >> 3) & 63;
        const int s   = (idx >> 9) & 3;
        const int r   = idx >> 11;
        const int tap = r % 9;
        const int ot  = r / 9;
        const int o   = ot * 16 + (L & 15);
        const int c   = s * 32 + (L >> 4) * 8 + j;
        wpo[idx] = (o < COFF) ? f2h(w_off[(size_t)(o * CIN + c) * Kn + tap])
                              : (unsigned short)0;
    }
}

// ---------------------------------------------------------------------------
// Fused kernel: round-5 structure (monolithic phase-1 window, wave-owns-
// outputs phase 2, depth-2 gather pipeline) + PRECOMPUTED SAMPLE TABLE:
//   After offl is published, 256 threads compute the 576 (px,tap) bilinear
//   records ONCE (round-5 recomputed each ~50-op chain 8x redundantly per
//   tap): 4 clamped corner indices packed u16x4 and 4 f16 weights
//   pre-broadcast as half2. prep_issue becomes 2 broadcast ds_reads +
//   unpack + 4 gathers (~20 VALU/tap vs ~100).
// LDS union (50,688 B -> 3 blocks/CU):
//   phase 1 : xw[198 slots][16 chunks] window (3 rows x 66 cols)
//   phase 2 : offl[27][64] f32 @0 (6,912B); smp4[2][64][8] @8192 (16,384B);
//             tabW[9][64] uint4 @24,576 (9,216B); tabIdx[9][64] uint2
//             @33,792 (4,608B) -- all inside the dead xw region.
// ---------------------------------------------------------------------------
__global__ __launch_bounds__(256) void fused_deform_kernel(
    const uint4* __restrict__ xT4, const uint4* __restrict__ wpo,
    const uint4* __restrict__ wpd, const float* __restrict__ b_off,
    float* __restrict__ out)
{
    __shared__ __align__(16) char lds[198 * 16 * 16];   // 50,688 B
    uint4* xw     = (uint4*)lds;
    float* offl   = (float*)lds;                        // 27*64*4 = 6,912 B
    uint4* smp4   = (uint4*)(lds + 8192);               // 16,384 B
    uint4* tabW   = (uint4*)(lds + 24576);              // 9*64*16 = 9,216 B
    uint2* tabIdx = (uint2*)(lds + 33792);              // 9*64*8  = 4,608 B

    const int bb   = blockIdx.x & 7;                    // batch -> XCD affinity
    const int pix0 = (blockIdx.x >> 3) * 64;
    const int h0   = pix0 >> 7;
    const int w0   = pix0 & 127;
    const int tid  = threadIdx.x;
    const int wv   = tid >> 6;
    const int lane = tid & 63;
    const int quad = lane >> 4;
    const int lrow = lane & 15;

    const uint4* xb = xT4 + (size_t)bb * HW * 16;

    // ======== phase 1: stage 3x66 window ========
    #pragma unroll
    for (int g = 0; g < 13; ++g) {
        const int idx = g * 256 + tid;
        if (idx < 198 * 16) {
            const int slot = idx >> 4;
            const int j    = idx & 15;
            const int r    = slot / 66;
            const int c    = slot - r * 66;
            const int y    = h0 + r - 1;
            const int x    = w0 + c - 1;
            const bool ok  = (y >= 0) & (y < Hn) & (x >= 0) & (x < Wn);
            uint4 v = make_uint4(0, 0, 0, 0);
            if (ok) v = xb[(size_t)(y * Wn + x) * 16 + j];
            xw[slot * 16 + (j ^ (slot & 7))] = v;
        }
    }
    __syncthreads();

    // ======== phase 1: offset-conv GEMM ========
    {
        const int ot   = wv >> 1;
        const int sub0 = (wv & 1) * 2;

        f32x4 oacc[2];
        #pragma unroll
        for (int t = 0; t < 2; ++t)
            #pragma unroll
            for (int r = 0; r < 4; ++r) {
                const int o = ot * 16 + quad * 4 + r;
                oacc[t][r] = (o < COFF) ? b_off[o] : 0.0f;
            }

        #pragma unroll
        for (int tap = 0; tap < 9; ++tap) {
            const int rr = tap / 3;
            const int cc = tap % 3;

            const uint4* ap = wpo + (size_t)((ot * 9 + tap) * 4) * 64 + lane;
            f16x8 a[4];
            #pragma unroll
            for (int s = 0; s < 4; ++s)
                a[s] = __builtin_bit_cast(f16x8, ap[s * 64]);

            #pragma unroll
            for (int t = 0; t < 2; ++t) {
                const int pl   = (sub0 + t) * 16 + lrow;
                const int slot = rr * 66 + pl + cc;
                const int base = slot * 16;
                const int sw   = slot & 7;
                #pragma unroll
                for (int s = 0; s < 4; ++s) {
                    const f16x8 bfrag = __builtin_bit_cast(f16x8,
                        xw[base + ((s * 4 + quad) ^ sw)]);
                    oacc[t] = __builtin_amdgcn_mfma_f32_16x16x32_f16(
                        a[s], bfrag, oacc[t], 0, 0, 0);
                }
            }
        }
        __syncthreads();   // all xw reads complete before offl overwrite

        #pragma unroll
        for (int t = 0; t < 2; ++t) {
            const int pl = (sub0 + t) * 16 + lrow;
            #pragma unroll
            for (int r = 0; r < 4; ++r) {
                const int o = ot * 16 + quad * 4 + r;
                if (o < COFF) offl[o * 64 + pl] = oacc[t][r];
            }
        }
        __syncthreads();   // offl visible to all
    }

    // ======== phase 1.5: build per-(px,tap) sample table (once) ========
    for (int e = tid; e < 9 * 64; e += 256) {
        const int k  = e >> 6;          // tap 0..8
        const int pl = e & 63;
        const int pG = pix0 + pl;
        const float dy = offl[(2 * k    ) * 64 + pl];
        const float dx = offl[(2 * k + 1) * 64 + pl];
        const float mk = offl[(18 + k   ) * 64 + pl];
        const float py  = (float)((pG >> 7)  + k / 3 - 1) + dy;
        const float pxf = (float)((pG & 127) + k % 3 - 1) + dx;
        const float y0f = floorf(py), x0f = floorf(pxf);
        const float fy = py - y0f,  fx = pxf - x0f;
        const int y0 = (int)y0f, x0 = (int)x0f;
        const int y1 = y0 + 1,   x1 = x0 + 1;
        const bool vy0 = (y0 >= 0) & (y0 < Hn);
        const bool vy1 = (y1 >= 0) & (y1 < Hn);
        const bool vx0 = (x0 >= 0) & (x0 < Wn);
        const bool vx1 = (x1 >= 0) & (x1 < Wn);
        const float w00 = (1.f - fy) * (1.f - fx) * (float)(vy0 & vx0) * mk;
        const float w01 = (1.f - fy) * fx         * (float)(vy0 & vx1) * mk;
        const float w10 = fy * (1.f - fx)         * (float)(vy1 & vx0) * mk;
        const float w11 = fy * fx                 * (float)(vy1 & vx1) * mk;
        const int y0c = min(max(y0, 0), Hn - 1);
        const int y1c = min(max(y1, 0), Hn - 1);
        const int x0c = min(max(x0, 0), Wn - 1);
        const int x1c = min(max(x1, 0), Wn - 1);
        const unsigned i00 = (unsigned)(y0c * Wn + x0c);
        const unsigned i01 = (unsigned)(y0c * Wn + x1c);
        const unsigned i10 = (unsigned)(y1c * Wn + x0c);
        const unsigned i11 = (unsigned)(y1c * Wn + x1c);
        const unsigned h00 = f2h(w00), h01 = f2h(w01);
        const unsigned h10 = f2h(w10), h11 = f2h(w11);
        tabW[e]   = make_uint4(h00 | (h00 << 16), h01 | (h01 << 16),
                               h10 | (h10 << 16), h11 | (h11 << 16));
        tabIdx[e] = make_uint2(i00 | (i01 << 16), i10 | (i11 << 16));
    }
    __syncthreads();   // table visible to all

    // ======== phase 2: deformable sampling + deform GEMM, depth-2 ========
    const int chunk = lane & 7;
    const int psub  = lane >> 3;

    // this lane's two gather pixels (g = 0,1), fixed for all taps
    int plg[2];
    #pragma unroll
    for (int g = 0; g < 2; ++g) plg[g] = g * 32 + wv * 8 + psub;

    f32x4 acc[4];
    #pragma unroll
    for (int i = 0; i < 4; ++i) acc[i] = (f32x4){0.f, 0.f, 0.f, 0.f};

    uint4   GB[2][8];        // [tap parity][corner*2 + g]
    __half2 WB[2][2][4];     // [tap parity][g][corner]
    f16x8   AF[2][2];        // [tap parity][k-half]

    auto prep_issue = [&](int k) {
        const int par = k & 1;
        #pragma unroll
        for (int g = 0; g < 2; ++g) {
            const int pl = plg[g];
            const uint4 wv4 = tabW[k * 64 + pl];    // broadcast ds_read_b128
            const uint2 iv  = tabIdx[k * 64 + pl];  // broadcast ds_read_b64
            WB[par][g][0] = u2h2(wv4.x);
            WB[par][g][1] = u2h2(wv4.y);
            WB[par][g][2] = u2h2(wv4.z);
            WB[par][g][3] = u2h2(wv4.w);
            const int i00 = (int)(iv.x & 0xFFFFu);
            const int i01 = (int)(iv.x >> 16);
            const int i10 = (int)(iv.y & 0xFFFFu);
            const int i11 = (int)(iv.y >> 16);
            GB[par][0 + g] = xb[(size_t)i00 * 16 + chunk];
            GB[par][2 + g] = xb[(size_t)i01 * 16 + chunk];
            GB[par][4 + g] = xb[(size_t)i10 * 16 + chunk];
            GB[par][6 + g] = xb[(size_t)i11 * 16 + chunk];
        }
    };

    auto blend_store = [&](int k) {
        const int par = k & 1;
        #pragma unroll
        for (int g = 0; g < 2; ++g) {
            const int pl = plg[g];
            const uint4 g00 = GB[par][0 + g], g01 = GB[par][2 + g];
            const uint4 g10 = GB[par][4 + g], g11 = GB[par][6 + g];
            const unsigned u00[4] = {g00.x, g00.y, g00.z, g00.w};
            const unsigned u01[4] = {g01.x, g01.y, g01.z, g01.w};
            const unsigned u10[4] = {g10.x, g10.y, g10.z, g10.w};
            const unsigned u11[4] = {g11.x, g11.y, g11.z, g11.w};
            unsigned pk[4];
            #pragma unroll
            for (int d = 0; d < 4; ++d) {
                __half2 s = __hmul2(u2h2(u00[d]), WB[par][g][0]);
                s = __hfma2(u2h2(u01[d]), WB[par][g][1], s);
                s = __hfma2(u2h2(u10[d]), WB[par][g][2], s);
                s = __hfma2(u2h2(u11[d]), WB[par][g][3], s);
                pk[d] = h22u(s);
            }
            smp4[par * 512 + pl * 8 + (chunk ^ (pl & 7))] =
                make_uint4(pk[0], pk[1], pk[2], pk[3]);
        }
    };

    auto load_af = [&](int k) {
        const uint4* wpk = wpd + (size_t)((wv * 9 + k) * 2) * 64 + lane;
        AF[k & 1][0] = __builtin_bit_cast(f16x8, wpk[0]);
        AF[k & 1][1] = __builtin_bit_cast(f16x8, wpk[64]);
    };

    // preamble: fill the 2-deep pipe
    prep_issue(0);
    prep_issue(1);
    load_af(0);
    blend_store(0);          // waits only tap-0 gathers
    __syncthreads();

    #pragma unroll
    for (int t = 0; t < Kn; ++t) {
        if (t + 1 < Kn) load_af(t + 1);       // A-frags for next tap
        if (t + 2 < Kn) prep_issue(t + 2);    // gathers fly for 2 taps

        const int buf = t & 1;
        #pragma unroll
        for (int nt = 0; nt < 4; ++nt) {
            const int pm = nt * 16 + lrow;
            const f16x8 b0 = __builtin_bit_cast(f16x8,
                smp4[buf * 512 + pm * 8 + ( quad      ^ (pm & 7))]);
            const f16x8 b1 = __builtin_bit_cast(f16x8,
                smp4[buf * 512 + pm * 8 + ((quad + 4) ^ (pm & 7))]);
            acc[nt] = __builtin_amdgcn_mfma_f32_16x16x32_f16(AF[buf][0], b0, acc[nt], 0, 0, 0);
            acc[nt] = __builtin_amdgcn_mfma_f32_16x16x32_f16(AF[buf][1], b1, acc[nt], 0, 0, 0);
        }

        if (t + 1 < Kn) {
            blend_store(t + 1);   // waits tap t+1 gathers; t+2 stay in flight
            __syncthreads();
        }
    }

    const int obase = (wv << 4) + (quad << 2);
    #pragma unroll
    for (int nt = 0; nt < 4; ++nt) {
        const int pp = pix0 + nt * 16 + lrow;
        #pragma unroll
        for (int r = 0; r < 4; ++r)
            out[(size_t)(bb * CO_ + obase + r) * HW + pp] = acc[nt][r];
    }
}

extern "C" void kernel_launch(void* const* d_in, const int* in_sizes, int n_in,
                              void* d_out, int out_size, void* d_ws, size_t ws_size,
                              hipStream_t stream) {
    const float* mem   = (const float*)d_in[0];
    const float* que   = (const float*)d_in[1];
    const float* w_off = (const float*)d_in[2];
    const float* b_off = (const float*)d_in[3];
    const float* w_def = (const float*)d_in[4];
    float* out = (float*)d_out;

    char* ws = (char*)d_ws;
    unsigned short* wpd = (unsigned short*)ws;             //  73,728 B
    unsigned short* wpo = (unsigned short*)(ws + 73728);   //  73,728 B
    uint4*          xT4 = (uint4*)(ws + 147456);           //  33,554,432 B

    transpose_kernel<<<2048, 256, 0, stream>>>(mem, que, xT4);
    wprep_all_kernel<<<288, 256, 0, stream>>>(w_def, w_off, wpd, wpo);
    fused_deform_kernel<<<2048, 256, 0, stream>>>(
        xT4, (const uint4*)wpo, (const uint4*)wpd, b_off, out);
}

// Round 7
// 161.999 us; speedup vs baseline: 1.0246x; 1.0246x over previous
//
#include <hip/hip_runtime.h>
#include <hip/hip_fp16.h>

#define Bn   8
#define CM_  64
#define CIN  128   // mem(64) + que(64)
#define CO_  64
#define Hn   128
#define Wn   128
#define Kn   9
#define COFF 27    // 18 offset + 9 mask channels
#define HW   (Hn * Wn)

typedef __attribute__((ext_vector_type(8))) _Float16 f16x8;  // 8 f16 = 4 VGPRs
typedef __attribute__((ext_vector_type(4))) float f32x4;

__device__ __forceinline__ unsigned h22u(__half2 h) {
    unsigned u; __builtin_memcpy(&u, &h, 4); return u;
}
__device__ __forceinline__ __half2 u2h2(unsigned u) {
    __half2 h; __builtin_memcpy(&h, &u, 4); return h;
}
__device__ __forceinline__ unsigned short f2h(float x) {
    __half h = __float2half(x);
    unsigned short u; __builtin_memcpy(&u, &h, 2); return u;
}

// ---------------------------------------------------------------------------
// Kernel P (merged): blocks [0,2048) transpose concat(mem,que) -> xT f16;
// blocks [2048,2336) pack w_def/w_off into MFMA A-fragment order.
//   wpd: idx = (((g*9+k)*2+f)*64+L)*8+j  -> W[o=g*16+(L&15)][c=f*32+(L>>4)*8+j]
//   wpo: idx = (((ot*9+tap)*4+s)*64+L)*8+j -> o=ot*16+(L&15) (pad 27->32)
// ---------------------------------------------------------------------------
__global__ __launch_bounds__(256) void prep_kernel(
    const float* __restrict__ mem, const float* __restrict__ que,
    uint4* __restrict__ xT4,
    const float* __restrict__ w_def, const float* __restrict__ w_off,
    unsigned short* __restrict__ wpd, unsigned short* __restrict__ wpo)
{
    __shared__ unsigned tile[64 * 65];
    const int tid = threadIdx.x;

    if (blockIdx.x >= 2048) {
        int idx = (blockIdx.x - 2048) * 256 + tid;
        if (idx < CO_ * CM_ * Kn) {
            const int j  = idx & 7;
            const int L  = (idx >> 3) & 63;
            const int f  = (idx >> 9) & 1;
            const int gk = idx >> 10;
            const int k  = gk % 9;
            const int g  = gk / 9;
            const int o  = g * 16 + (L & 15);
            const int c  = f * 32 + (L >> 4) * 8 + j;
            wpd[idx] = f2h(w_def[(size_t)(o * CM_ + c) * Kn + k]);
            return;
        }
        idx -= CO_ * CM_ * Kn;
        if (idx < 2 * 9 * 4 * 64 * 8) {
            const int j   = idx & 7;
            const int L   = (idx >> 3) & 63;
            const int s   = (idx >> 9) & 3;
            const int r   = idx >> 11;
            const int tap = r % 9;
            const int ot  = r / 9;
            const int o   = ot * 16 + (L & 15);
            const int c   = s * 32 + (L >> 4) * 8 + j;
            wpo[idx] = (o < COFF) ? f2h(w_off[(size_t)(o * CIN + c) * Kn + tap])
                                  : (unsigned short)0;
        }
        return;
    }

    const int bb   = blockIdx.x & 7;
    const int pix0 = (blockIdx.x >> 3) * 64;
    const int pxL  = tid & 63;
    const int cg   = tid >> 6;

    const float* mb = mem + (size_t)bb * CM_ * HW + pix0 + pxL;
    const float* qb = que + (size_t)bb * CM_ * HW + pix0 + pxL;

    #pragma unroll
    for (int i = 0; i < 16; ++i) {
        const int c = cg * 32 + 2 * i;
        const float v0 = (c < CM_) ? mb[(size_t)c * HW]       : qb[(size_t)(c - CM_) * HW];
        const float v1 = (c + 1 < CM_) ? mb[(size_t)(c + 1) * HW] : qb[(size_t)(c + 1 - CM_) * HW];
        tile[pxL * 65 + cg * 16 + i] = h22u(__floats2half2_rn(v0, v1));
    }
    __syncthreads();

    uint4* dst = xT4 + (size_t)(bb * HW + pix0) * 16;
    #pragma unroll
    for (int p = 0; p < 4; ++p) {
        const int G  = p * 256 + tid;
        const int px = G >> 4;
        const int u  = G & 15;
        uint4 v;
        v.x = tile[px * 65 + u * 4 + 0];
        v.y = tile[px * 65 + u * 4 + 1];
        v.z = tile[px * 65 + u * 4 + 2];
        v.w = tile[px * 65 + u * 4 + 3];
        dst[G] = v;
    }
}

// ---------------------------------------------------------------------------
// Fused kernel, round-6 pipeline + COMPACT LDS for 4 blocks/CU (was 3):
//   phase 1 : channel-split window (round-1-verified), xw = 198 slots x 8
//             chunks = 25,344 B, two 64-ch halves, same total L2 bytes.
//   phase 1.5: per-(px,tap) sample table (subsumes offl for phase 2).
//   phase 2 : depth-2 gather pipeline, table-driven prep (round-6).
// LDS map (37,120 B total -> 4 blocks/CU):
//   [0, 25,344)      xw (phase 1 only; dead after)
//   [0, 16,384)      smp4 (phase 2; overlays dead xw)
//   [16,384, 25,600) tabW   9*64 uint4 (phase 1.5+2; overlays dead xw)
//   [25,600, 30,208) tabIdx 9*64 uint2
//   [30,208, 37,120) offl 27*64 f32 (end of phase 1 .. phase 1.5 only)
// ---------------------------------------------------------------------------
__global__ __launch_bounds__(256) void fused_deform_kernel(
    const uint4* __restrict__ xT4, const uint4* __restrict__ wpo,
    const uint4* __restrict__ wpd, const float* __restrict__ b_off,
    float* __restrict__ out)
{
    __shared__ __align__(16) char lds[37120];
    uint4* xw     = (uint4*)lds;
    uint4* smp4   = (uint4*)lds;                        // 16,384 B
    uint4* tabW   = (uint4*)(lds + 16384);              // 9,216 B
    uint2* tabIdx = (uint2*)(lds + 25600);              // 4,608 B
    float* offl   = (float*)(lds + 30208);              // 6,912 B

    const int bb   = blockIdx.x & 7;                    // batch -> XCD affinity
    const int pix0 = (blockIdx.x >> 3) * 64;
    const int h0   = pix0 >> 7;
    const int w0   = pix0 & 127;
    const int tid  = threadIdx.x;
    const int wv   = tid >> 6;
    const int lane = tid & 63;
    const int quad = lane >> 4;
    const int lrow = lane & 15;

    const uint4* xb = xT4 + (size_t)bb * HW * 16;

    // ======== phase 1: offset-conv GEMM, two 64-channel halves ========
    {
        const int ot   = wv >> 1;
        const int sub0 = (wv & 1) * 2;

        f32x4 oacc[2];
        #pragma unroll
        for (int t = 0; t < 2; ++t)
            #pragma unroll
            for (int r = 0; r < 4; ++r) {
                const int o = ot * 16 + quad * 4 + r;
                oacc[t][r] = (o < COFF) ? b_off[o] : 0.0f;
            }

        #pragma unroll
        for (int Hh = 0; Hh < 2; ++Hh) {
            // ---- stage 3x66 window, 64-channel half Hh ----
            #pragma unroll
            for (int g = 0; g < 7; ++g) {
                const int idx = g * 256 + tid;
                if (idx < 198 * 8) {
                    const int slot = idx >> 3;
                    const int j    = idx & 7;
                    const int r    = slot / 66;
                    const int c    = slot - r * 66;
                    const int y    = h0 + r - 1;
                    const int x    = w0 + c - 1;
                    const bool ok  = (y >= 0) & (y < Hn) & (x >= 0) & (x < Wn);
                    uint4 v = make_uint4(0, 0, 0, 0);
                    if (ok) v = xb[(size_t)(y * Wn + x) * 16 + Hh * 8 + j];
                    xw[slot * 8 + (j ^ (slot & 7))] = v;
                }
            }
            __syncthreads();

            #pragma unroll
            for (int tap = 0; tap < 9; ++tap) {
                const int rr = tap / 3;
                const int cc = tap % 3;

                const uint4* ap = wpo
                    + (size_t)((ot * 9 + tap) * 4 + Hh * 2) * 64 + lane;
                f16x8 a[2];
                #pragma unroll
                for (int s = 0; s < 2; ++s)
                    a[s] = __builtin_bit_cast(f16x8, ap[s * 64]);

                #pragma unroll
                for (int t = 0; t < 2; ++t) {
                    const int pl   = (sub0 + t) * 16 + lrow;
                    const int slot = rr * 66 + pl + cc;
                    const int base = slot * 8;
                    const int sw   = slot & 7;
                    #pragma unroll
                    for (int s = 0; s < 2; ++s) {
                        const f16x8 bfrag = __builtin_bit_cast(f16x8,
                            xw[base + ((s * 4 + quad) ^ sw)]);
                        oacc[t] = __builtin_amdgcn_mfma_f32_16x16x32_f16(
                            a[s], bfrag, oacc[t], 0, 0, 0);
                    }
                }
            }
            if (Hh == 0) __syncthreads();   // xw reads done before restage
        }

        // offl region [30,208+) is disjoint from xw: no pre-barrier needed
        #pragma unroll
        for (int t = 0; t < 2; ++t) {
            const int pl = (sub0 + t) * 16 + lrow;
            #pragma unroll
            for (int r = 0; r < 4; ++r) {
                const int o = ot * 16 + quad * 4 + r;
                if (o < COFF) offl[o * 64 + pl] = oacc[t][r];
            }
        }
        __syncthreads();   // offl visible; all xw reads done -> tab may overlay
    }

    // ======== phase 1.5: build per-(px,tap) sample table (once) ========
    for (int e = tid; e < 9 * 64; e += 256) {
        const int k  = e >> 6;          // tap 0..8
        const int pl = e & 63;
        const int pG = pix0 + pl;
        const float dy = offl[(2 * k    ) * 64 + pl];
        const float dx = offl[(2 * k + 1) * 64 + pl];
        const float mk = offl[(18 + k   ) * 64 + pl];
        const float py  = (float)((pG >> 7)  + k / 3 - 1) + dy;
        const float pxf = (float)((pG & 127) + k % 3 - 1) + dx;
        const float y0f = floorf(py), x0f = floorf(pxf);
        const float fy = py - y0f,  fx = pxf - x0f;
        const int y0 = (int)y0f, x0 = (int)x0f;
        const int y1 = y0 + 1,   x1 = x0 + 1;
        const bool vy0 = (y0 >= 0) & (y0 < Hn);
        const bool vy1 = (y1 >= 0) & (y1 < Hn);
        const bool vx0 = (x0 >= 0) & (x0 < Wn);
        const bool vx1 = (x1 >= 0) & (x1 < Wn);
        const float w00 = (1.f - fy) * (1.f - fx) * (float)(vy0 & vx0) * mk;
        const float w01 = (1.f - fy) * fx         * (float)(vy0 & vx1) * mk;
        const float w10 = fy * (1.f - fx)         * (float)(vy1 & vx0) * mk;
        const float w11 = fy * fx                 * (float)(vy1 & vx1) * mk;
        const int y0c = min(max(y0, 0), Hn - 1);
        const int y1c = min(max(y1, 0), Hn - 1);
        const int x0c = min(max(x0, 0), Wn - 1);
        const int x1c = min(max(x1, 0), Wn - 1);
        const unsigned i00 = (unsigned)(y0c * Wn + x0c);
        const unsigned i01 = (unsigned)(y0c * Wn + x1c);
        const unsigned i10 = (unsigned)(y1c * Wn + x0c);
        const unsigned i11 = (unsigned)(y1c * Wn + x1c);
        const unsigned h00 = f2h(w00), h01 = f2h(w01);
        const unsigned h10 = f2h(w10), h11 = f2h(w11);
        tabW[e]   = make_uint4(h00 | (h00 << 16), h01 | (h01 << 16),
                               h10 | (h10 << 16), h11 | (h11 << 16));
        tabIdx[e] = make_uint2(i00 | (i01 << 16), i10 | (i11 << 16));
    }
    __syncthreads();   // table visible to all; offl and xw now dead

    // ======== phase 2: deformable sampling + deform GEMM, depth-2 ========
    const int chunk = lane & 7;
    const int psub  = lane >> 3;

    int plg[2];
    #pragma unroll
    for (int g = 0; g < 2; ++g) plg[g] = g * 32 + wv * 8 + psub;

    f32x4 acc[4];
    #pragma unroll
    for (int i = 0; i < 4; ++i) acc[i] = (f32x4){0.f, 0.f, 0.f, 0.f};

    uint4   GB[2][8];        // [tap parity][corner*2 + g]
    __half2 WB[2][2][4];     // [tap parity][g][corner]
    f16x8   AF[2][2];        // [tap parity][k-half]

    auto prep_issue = [&](int k) {
        const int par = k & 1;
        #pragma unroll
        for (int g = 0; g < 2; ++g) {
            const int pl = plg[g];
            const uint4 wv4 = tabW[k * 64 + pl];    // broadcast ds_read_b128
            const uint2 iv  = tabIdx[k * 64 + pl];  // broadcast ds_read_b64
            WB[par][g][0] = u2h2(wv4.x);
            WB[par][g][1] = u2h2(wv4.y);
            WB[par][g][2] = u2h2(wv4.z);
            WB[par][g][3] = u2h2(wv4.w);
            const int i00 = (int)(iv.x & 0xFFFFu);
            const int i01 = (int)(iv.x >> 16);
            const int i10 = (int)(iv.y & 0xFFFFu);
            const int i11 = (int)(iv.y >> 16);
            GB[par][0 + g] = xb[(size_t)i00 * 16 + chunk];
            GB[par][2 + g] = xb[(size_t)i01 * 16 + chunk];
            GB[par][4 + g] = xb[(size_t)i10 * 16 + chunk];
            GB[par][6 + g] = xb[(size_t)i11 * 16 + chunk];
        }
    };

    auto blend_store = [&](int k) {
        const int par = k & 1;
        #pragma unroll
        for (int g = 0; g < 2; ++g) {
            const int pl = plg[g];
            const uint4 g00 = GB[par][0 + g], g01 = GB[par][2 + g];
            const uint4 g10 = GB[par][4 + g], g11 = GB[par][6 + g];
            const unsigned u00[4] = {g00.x, g00.y, g00.z, g00.w};
            const unsigned u01[4] = {g01.x, g01.y, g01.z, g01.w};
            const unsigned u10[4] = {g10.x, g10.y, g10.z, g10.w};
            const unsigned u11[4] = {g11.x, g11.y, g11.z, g11.w};
            unsigned pk[4];
            #pragma unroll
            for (int d = 0; d < 4; ++d) {
                __half2 s = __hmul2(u2h2(u00[d]), WB[par][g][0]);
                s = __hfma2(u2h2(u01[d]), WB[par][g][1], s);
                s = __hfma2(u2h2(u10[d]), WB[par][g][2], s);
                s = __hfma2(u2h2(u11[d]), WB[par][g][3], s);
                pk[d] = h22u(s);
            }
            smp4[par * 512 + pl * 8 + (chunk ^ (pl & 7))] =
                make_uint4(pk[0], pk[1], pk[2], pk[3]);
        }
    };

    auto load_af = [&](int k) {
        const uint4* wpk = wpd + (size_t)((wv * 9 + k) * 2) * 64 + lane;
        AF[k & 1][0] = __builtin_bit_cast(f16x8, wpk[0]);
        AF[k & 1][1] = __builtin_bit_cast(f16x8, wpk[64]);
    };

    // preamble: fill the 2-deep pipe
    prep_issue(0);
    prep_issue(1);
    load_af(0);
    blend_store(0);          // waits only tap-0 gathers
    __syncthreads();

    #pragma unroll
    for (int t = 0; t < Kn; ++t) {
        if (t + 1 < Kn) load_af(t + 1);       // A-frags for next tap
        if (t + 2 < Kn) prep_issue(t + 2);    // gathers fly for 2 taps

        const int buf = t & 1;
        #pragma unroll
        for (int nt = 0; nt < 4; ++nt) {
            const int pm = nt * 16 + lrow;
            const f16x8 b0 = __builtin_bit_cast(f16x8,
                smp4[buf * 512 + pm * 8 + ( quad      ^ (pm & 7))]);
            const f16x8 b1 = __builtin_bit_cast(f16x8,
                smp4[buf * 512 + pm * 8 + ((quad + 4) ^ (pm & 7))]);
            acc[nt] = __builtin_amdgcn_mfma_f32_16x16x32_f16(AF[buf][0], b0, acc[nt], 0, 0, 0);
            acc[nt] = __builtin_amdgcn_mfma_f32_16x16x32_f16(AF[buf][1], b1, acc[nt], 0, 0, 0);
        }

        if (t + 1 < Kn) {
            blend_store(t + 1);   // waits tap t+1 gathers; t+2 stay in flight
            __syncthreads();
        }
    }

    const int obase = (wv << 4) + (quad << 2);
    #pragma unroll
    for (int nt = 0; nt < 4; ++nt) {
        const int pp = pix0 + nt * 16 + lrow;
        #pragma unroll
        for (int r = 0; r < 4; ++r)
            out[(size_t)(bb * CO_ + obase + r) * HW + pp] = acc[nt][r];
    }
}

extern "C" void kernel_launch(void* const* d_in, const int* in_sizes, int n_in,
                              void* d_out, int out_size, void* d_ws, size_t ws_size,
                              hipStream_t stream) {
    const float* mem   = (const float*)d_in[0];
    const float* que   = (const float*)d_in[1];
    const float* w_off = (const float*)d_in[2];
    const float* b_off = (const float*)d_in[3];
    const float* w_def = (const float*)d_in[4];
    float* out = (float*)d_out;

    char* ws = (char*)d_ws;
    unsigned short* wpd = (unsigned short*)ws;             //  73,728 B
    unsigned short* wpo = (unsigned short*)(ws + 73728);   //  73,728 B
    uint4*          xT4 = (uint4*)(ws + 147456);           //  33,554,432 B

    prep_kernel<<<2336, 256, 0, stream>>>(mem, que, xT4, w_def, w_off, wpd, wpo);
    fused_deform_kernel<<<2048, 256, 0, stream>>>(
        xT4, (const uint4*)wpo, (const uint4*)wpd, b_off, out);
}

// Round 8
// 160.925 us; speedup vs baseline: 1.0314x; 1.0067x over previous
//
#include <hip/hip_runtime.h>
#include <hip/hip_fp16.h>

#define Bn   8
#define CM_  64
#define CIN  128   // mem(64) + que(64)
#define CO_  64
#define Hn   128
#define Wn   128
#define Kn   9
#define COFF 27    // 18 offset + 9 mask channels
#define HW   (Hn * Wn)

typedef __attribute__((ext_vector_type(8))) _Float16 f16x8;  // 8 f16 = 4 VGPRs
typedef __attribute__((ext_vector_type(4))) float f32x4;

__device__ __forceinline__ unsigned h22u(__half2 h) {
    unsigned u; __builtin_memcpy(&u, &h, 4); return u;
}
__device__ __forceinline__ __half2 u2h2(unsigned u) {
    __half2 h; __builtin_memcpy(&h, &u, 4); return h;
}
__device__ __forceinline__ unsigned short f2h(float x) {
    __half h = __float2half(x);
    unsigned short u; __builtin_memcpy(&u, &h, 2); return u;
}
// broadcast low/high f16 of a u32 into both halves (one v_perm_b32)
__device__ __forceinline__ __half2 bcast_lo(unsigned u) {
    return u2h2(__builtin_amdgcn_perm(0u, u, 0x01000100u));
}
__device__ __forceinline__ __half2 bcast_hi(unsigned u) {
    return u2h2(__builtin_amdgcn_perm(0u, u, 0x03020302u));
}

// ---------------------------------------------------------------------------
// Kernel P (merged): blocks [0,2048) transpose concat(mem,que) -> xT f16;
// blocks [2048,2336) pack w_def/w_off into MFMA A-fragment order.
//   wpd: idx = (((g*9+k)*2+f)*64+L)*8+j  -> W[o=g*16+(L&15)][c=f*32+(L>>4)*8+j]
//   wpo: idx = (((ot*9+tap)*4+s)*64+L)*8+j -> o=ot*16+(L&15) (pad 27->32)
// ---------------------------------------------------------------------------
__global__ __launch_bounds__(256) void prep_kernel(
    const float* __restrict__ mem, const float* __restrict__ que,
    uint4* __restrict__ xT4,
    const float* __restrict__ w_def, const float* __restrict__ w_off,
    unsigned short* __restrict__ wpd, unsigned short* __restrict__ wpo)
{
    __shared__ unsigned tile[64 * 65];
    const int tid = threadIdx.x;

    if (blockIdx.x >= 2048) {
        int idx = (blockIdx.x - 2048) * 256 + tid;
        if (idx < CO_ * CM_ * Kn) {
            const int j  = idx & 7;
            const int L  = (idx >> 3) & 63;
            const int f  = (idx >> 9) & 1;
            const int gk = idx >> 10;
            const int k  = gk % 9;
            const int g  = gk / 9;
            const int o  = g * 16 + (L & 15);
            const int c  = f * 32 + (L >> 4) * 8 + j;
            wpd[idx] = f2h(w_def[(size_t)(o * CM_ + c) * Kn + k]);
            return;
        }
        idx -= CO_ * CM_ * Kn;
        if (idx < 2 * 9 * 4 * 64 * 8) {
            const int j   = idx & 7;
            const int L   = (idx >> 3) & 63;
            const int s   = (idx >> 9) & 3;
            const int r   = idx >> 11;
            const int tap = r % 9;
            const int ot  = r / 9;
            const int o   = ot * 16 + (L & 15);
            const int c   = s * 32 + (L >> 4) * 8 + j;
            wpo[idx] = (o < COFF) ? f2h(w_off[(size_t)(o * CIN + c) * Kn + tap])
                                  : (unsigned short)0;
        }
        return;
    }

    const int bb   = blockIdx.x & 7;
    const int pix0 = (blockIdx.x >> 3) * 64;
    const int pxL  = tid & 63;
    const int cg   = tid >> 6;

    const float* mb = mem + (size_t)bb * CM_ * HW + pix0 + pxL;
    const float* qb = que + (size_t)bb * CM_ * HW + pix0 + pxL;

    #pragma unroll
    for (int i = 0; i < 16; ++i) {
        const int c = cg * 32 + 2 * i;
        const float v0 = (c < CM_) ? mb[(size_t)c * HW]       : qb[(size_t)(c - CM_) * HW];
        const float v1 = (c + 1 < CM_) ? mb[(size_t)(c + 1) * HW] : qb[(size_t)(c + 1 - CM_) * HW];
        tile[pxL * 65 + cg * 16 + i] = h22u(__floats2half2_rn(v0, v1));
    }
    __syncthreads();

    uint4* dst = xT4 + (size_t)(bb * HW + pix0) * 16;
    #pragma unroll
    for (int p = 0; p < 4; ++p) {
        const int G  = p * 256 + tid;
        const int px = G >> 4;
        const int u  = G & 15;
        uint4 v;
        v.x = tile[px * 65 + u * 4 + 0];
        v.y = tile[px * 65 + u * 4 + 1];
        v.z = tile[px * 65 + u * 4 + 2];
        v.w = tile[px * 65 + u * 4 + 3];
        dst[G] = v;
    }
}

// ---------------------------------------------------------------------------
// Fused kernel, round-7 pipeline + LDS squeezed under 26 KB for 5 blocks/CU
// on the observed ~128KB effective LDS pool (r0/r1/r2/r6/r7 occupancy fits
// pool=128K, not 160K):
//   - offl overlays the smp4 region (extra barrier after phase-1 GEMM).
//   - tabW+tabIdx merged into ONE uint4/entry: idx u16x4 in .x/.y, weights
//     f16x4 packed in .z/.w (unpacked via 1 v_perm each). prep: 1 ds_read.
// LDS map (25,600 B total -> 5 blocks/CU @128K pool):
//   [0, 25,344)      xw (phase 1 only; dead after final phase-1 barrier)
//   [0, 16,384)      smp4 (phase 2) / offl 27*64 f32 [0,6912) (ph1->1.5 only)
//   [16,384, 25,600) tab 9*64 uint4 (phase 1.5 write, phase 2 read)
// ---------------------------------------------------------------------------
__global__ __launch_bounds__(256) void fused_deform_kernel(
    const uint4* __restrict__ xT4, const uint4* __restrict__ wpo,
    const uint4* __restrict__ wpd, const float* __restrict__ b_off,
    float* __restrict__ out)
{
    __shared__ __align__(16) char lds[25600];
    uint4* xw   = (uint4*)lds;
    uint4* smp4 = (uint4*)lds;                          // 16,384 B
    float* offl = (float*)lds;                          // 6,912 B (transient)
    uint4* tab  = (uint4*)(lds + 16384);                // 9,216 B

    const int bb   = blockIdx.x & 7;                    // batch -> XCD affinity
    const int pix0 = (blockIdx.x >> 3) * 64;
    const int h0   = pix0 >> 7;
    const int w0   = pix0 & 127;
    const int tid  = threadIdx.x;
    const int wv   = tid >> 6;
    const int lane = tid & 63;
    const int quad = lane >> 4;
    const int lrow = lane & 15;

    const uint4* xb = xT4 + (size_t)bb * HW * 16;

    // ======== phase 1: offset-conv GEMM, two 64-channel halves ========
    {
        const int ot   = wv >> 1;
        const int sub0 = (wv & 1) * 2;

        f32x4 oacc[2];
        #pragma unroll
        for (int t = 0; t < 2; ++t)
            #pragma unroll
            for (int r = 0; r < 4; ++r) {
                const int o = ot * 16 + quad * 4 + r;
                oacc[t][r] = (o < COFF) ? b_off[o] : 0.0f;
            }

        #pragma unroll
        for (int Hh = 0; Hh < 2; ++Hh) {
            // ---- stage 3x66 window, 64-channel half Hh ----
            #pragma unroll
            for (int g = 0; g < 7; ++g) {
                const int idx = g * 256 + tid;
                if (idx < 198 * 8) {
                    const int slot = idx >> 3;
                    const int j    = idx & 7;
                    const int r    = slot / 66;
                    const int c    = slot - r * 66;
                    const int y    = h0 + r - 1;
                    const int x    = w0 + c - 1;
                    const bool ok  = (y >= 0) & (y < Hn) & (x >= 0) & (x < Wn);
                    uint4 v = make_uint4(0, 0, 0, 0);
                    if (ok) v = xb[(size_t)(y * Wn + x) * 16 + Hh * 8 + j];
                    xw[slot * 8 + (j ^ (slot & 7))] = v;
                }
            }
            __syncthreads();

            #pragma unroll
            for (int tap = 0; tap < 9; ++tap) {
                const int rr = tap / 3;
                const int cc = tap % 3;

                const uint4* ap = wpo
                    + (size_t)((ot * 9 + tap) * 4 + Hh * 2) * 64 + lane;
                f16x8 a[2];
                #pragma unroll
                for (int s = 0; s < 2; ++s)
                    a[s] = __builtin_bit_cast(f16x8, ap[s * 64]);

                #pragma unroll
                for (int t = 0; t < 2; ++t) {
                    const int pl   = (sub0 + t) * 16 + lrow;
                    const int slot = rr * 66 + pl + cc;
                    const int base = slot * 8;
                    const int sw   = slot & 7;
                    #pragma unroll
                    for (int s = 0; s < 2; ++s) {
                        const f16x8 bfrag = __builtin_bit_cast(f16x8,
                            xw[base + ((s * 4 + quad) ^ sw)]);
                        oacc[t] = __builtin_amdgcn_mfma_f32_16x16x32_f16(
                            a[s], bfrag, oacc[t], 0, 0, 0);
                    }
                }
            }
            __syncthreads();   // Hh=0: before restage; Hh=1: xw reads done
                               //   before offl overlays xw bytes [0,6912)
        }

        #pragma unroll
        for (int t = 0; t < 2; ++t) {
            const int pl = (sub0 + t) * 16 + lrow;
            #pragma unroll
            for (int r = 0; r < 4; ++r) {
                const int o = ot * 16 + quad * 4 + r;
                if (o < COFF) offl[o * 64 + pl] = oacc[t][r];
            }
        }
        __syncthreads();   // offl visible to all
    }

    // ======== phase 1.5: build per-(px,tap) sample table (once) ========
    // tab[e] = { i00|i01<<16, i10|i11<<16, h00|h01<<16, h10|h11<<16 }
    for (int e = tid; e < 9 * 64; e += 256) {
        const int k  = e >> 6;          // tap 0..8
        const int pl = e & 63;
        const int pG = pix0 + pl;
        const float dy = offl[(2 * k    ) * 64 + pl];
        const float dx = offl[(2 * k + 1) * 64 + pl];
        const float mk = offl[(18 + k   ) * 64 + pl];
        const float py  = (float)((pG >> 7)  + k / 3 - 1) + dy;
        const float pxf = (float)((pG & 127) + k % 3 - 1) + dx;
        const float y0f = floorf(py), x0f = floorf(pxf);
        const float fy = py - y0f,  fx = pxf - x0f;
        const int y0 = (int)y0f, x0 = (int)x0f;
        const int y1 = y0 + 1,   x1 = x0 + 1;
        const bool vy0 = (y0 >= 0) & (y0 < Hn);
        const bool vy1 = (y1 >= 0) & (y1 < Hn);
        const bool vx0 = (x0 >= 0) & (x0 < Wn);
        const bool vx1 = (x1 >= 0) & (x1 < Wn);
        const float w00 = (1.f - fy) * (1.f - fx) * (float)(vy0 & vx0) * mk;
        const float w01 = (1.f - fy) * fx         * (float)(vy0 & vx1) * mk;
        const float w10 = fy * (1.f - fx)         * (float)(vy1 & vx0) * mk;
        const float w11 = fy * fx                 * (float)(vy1 & vx1) * mk;
        const int y0c = min(max(y0, 0), Hn - 1);
        const int y1c = min(max(y1, 0), Hn - 1);
        const int x0c = min(max(x0, 0), Wn - 1);
        const int x1c = min(max(x1, 0), Wn - 1);
        const unsigned i00 = (unsigned)(y0c * Wn + x0c);
        const unsigned i01 = (unsigned)(y0c * Wn + x1c);
        const unsigned i10 = (unsigned)(y1c * Wn + x0c);
        const unsigned i11 = (unsigned)(y1c * Wn + x1c);
        tab[e] = make_uint4(i00 | (i01 << 16), i10 | (i11 << 16),
                            (unsigned)f2h(w00) | ((unsigned)f2h(w01) << 16),
                            (unsigned)f2h(w10) | ((unsigned)f2h(w11) << 16));
    }
    __syncthreads();   // table visible; offl and xw now dead

    // ======== phase 2: deformable sampling + deform GEMM, depth-2 ========
    const int chunk = lane & 7;
    const int psub  = lane >> 3;

    int plg[2];
    #pragma unroll
    for (int g = 0; g < 2; ++g) plg[g] = g * 32 + wv * 8 + psub;

    f32x4 acc[4];
    #pragma unroll
    for (int i = 0; i < 4; ++i) acc[i] = (f32x4){0.f, 0.f, 0.f, 0.f};

    uint4   GB[2][8];        // [tap parity][corner*2 + g]
    __half2 WB[2][2][4];     // [tap parity][g][corner]
    f16x8   AF[2][2];        // [tap parity][k-half]

    auto prep_issue = [&](int k) {
        const int par = k & 1;
        #pragma unroll
        for (int g = 0; g < 2; ++g) {
            const int pl = plg[g];
            const uint4 tv = tab[k * 64 + pl];      // 1 broadcast ds_read_b128
            WB[par][g][0] = bcast_lo(tv.z);
            WB[par][g][1] = bcast_hi(tv.z);
            WB[par][g][2] = bcast_lo(tv.w);
            WB[par][g][3] = bcast_hi(tv.w);
            const int i00 = (int)(tv.x & 0xFFFFu);
            const int i01 = (int)(tv.x >> 16);
            const int i10 = (int)(tv.y & 0xFFFFu);
            const int i11 = (int)(tv.y >> 16);
            GB[par][0 + g] = xb[(size_t)i00 * 16 + chunk];
            GB[par][2 + g] = xb[(size_t)i01 * 16 + chunk];
            GB[par][4 + g] = xb[(size_t)i10 * 16 + chunk];
            GB[par][6 + g] = xb[(size_t)i11 * 16 + chunk];
        }
    };

    auto blend_store = [&](int k) {
        const int par = k & 1;
        #pragma unroll
        for (int g = 0; g < 2; ++g) {
            const int pl = plg[g];
            const uint4 g00 = GB[par][0 + g], g01 = GB[par][2 + g];
            const uint4 g10 = GB[par][4 + g], g11 = GB[par][6 + g];
            const unsigned u00[4] = {g00.x, g00.y, g00.z, g00.w};
            const unsigned u01[4] = {g01.x, g01.y, g01.z, g01.w};
            const unsigned u10[4] = {g10.x, g10.y, g10.z, g10.w};
            const unsigned u11[4] = {g11.x, g11.y, g11.z, g11.w};
            unsigned pk[4];
            #pragma unroll
            for (int d = 0; d < 4; ++d) {
                __half2 s = __hmul2(u2h2(u00[d]), WB[par][g][0]);
                s = __hfma2(u2h2(u01[d]), WB[par][g][1], s);
                s = __hfma2(u2h2(u10[d]), WB[par][g][2], s);
                s = __hfma2(u2h2(u11[d]), WB[par][g][3], s);
                pk[d] = h22u(s);
            }
            smp4[par * 512 + pl * 8 + (chunk ^ (pl & 7))] =
                make_uint4(pk[0], pk[1], pk[2], pk[3]);
        }
    };

    auto load_af = [&](int k) {
        const uint4* wpk = wpd + (size_t)((wv * 9 + k) * 2) * 64 + lane;
        AF[k & 1][0] = __builtin_bit_cast(f16x8, wpk[0]);
        AF[k & 1][1] = __builtin_bit_cast(f16x8, wpk[64]);
    };

    // preamble: fill the 2-deep pipe
    prep_issue(0);
    prep_issue(1);
    load_af(0);
    blend_store(0);          // waits only tap-0 gathers
    __syncthreads();

    #pragma unroll
    for (int t = 0; t < Kn; ++t) {
        if (t + 1 < Kn) load_af(t + 1);       // A-frags for next tap
        if (t + 2 < Kn) prep_issue(t + 2);    // gathers fly for 2 taps

        const int buf = t & 1;
        #pragma unroll
        for (int nt = 0; nt < 4; ++nt) {
            const int pm = nt * 16 + lrow;
            const f16x8 b0 = __builtin_bit_cast(f16x8,
                smp4[buf * 512 + pm * 8 + ( quad      ^ (pm & 7))]);
            const f16x8 b1 = __builtin_bit_cast(f16x8,
                smp4[buf * 512 + pm * 8 + ((quad + 4) ^ (pm & 7))]);
            acc[nt] = __builtin_amdgcn_mfma_f32_16x16x32_f16(AF[buf][0], b0, acc[nt], 0, 0, 0);
            acc[nt] = __builtin_amdgcn_mfma_f32_16x16x32_f16(AF[buf][1], b1, acc[nt], 0, 0, 0);
        }

        if (t + 1 < Kn) {
            blend_store(t + 1);   // waits tap t+1 gathers; t+2 stay in flight
            __syncthreads();
        }
    }

    const int obase = (wv << 4) + (quad << 2);
    #pragma unroll
    for (int nt = 0; nt < 4; ++nt) {
        const int pp = pix0 + nt * 16 + lrow;
        #pragma unroll
        for (int r = 0; r < 4; ++r)
            out[(size_t)(bb * CO_ + obase + r) * HW + pp] = acc[nt][r];
    }
}

extern "C" void kernel_launch(void* const* d_in, const int* in_sizes, int n_in,
                              void* d_out, int out_size, void* d_ws, size_t ws_size,
                              hipStream_t stream) {
    const float* mem   = (const float*)d_in[0];
    const float* que   = (const float*)d_in[1];
    const float* w_off = (const float*)d_in[2];
    const float* b_off = (const float*)d_in[3];
    const float* w_def = (const float*)d_in[4];
    float* out = (float*)d_out;

    char* ws = (char*)d_ws;
    unsigned short* wpd = (unsigned short*)ws;             //  73,728 B
    unsigned short* wpo = (unsigned short*)(ws + 73728);   //  73,728 B
    uint4*          xT4 = (uint4*)(ws + 147456);           //  33,554,432 B

    prep_kernel<<<2336, 256, 0, stream>>>(mem, que, xT4, w_def, w_off, wpd, wpo);
    fused_deform_kernel<<<2048, 256, 0, stream>>>(
        xT4, (const uint4*)wpo, (const uint4*)wpd, b_off, out);
}

// Round 9
// 160.300 us; speedup vs baseline: 1.0355x; 1.0039x over previous
//
#include <hip/hip_runtime.h>
#include <hip/hip_fp16.h>

#define Bn   8
#define CM_  64
#define CIN  128   // mem(64) + que(64)
#define CO_  64
#define Hn   128
#define Wn   128
#define Kn   9
#define COFF 27    // 18 offset + 9 mask channels
#define HW   (Hn * Wn)

typedef __attribute__((ext_vector_type(8))) _Float16 f16x8;  // 8 f16 = 4 VGPRs
typedef __attribute__((ext_vector_type(4))) float f32x4;

__device__ __forceinline__ unsigned h22u(__half2 h) {
    unsigned u; __builtin_memcpy(&u, &h, 4); return u;
}
__device__ __forceinline__ __half2 u2h2(unsigned u) {
    __half2 h; __builtin_memcpy(&h, &u, 4); return h;
}
__device__ __forceinline__ unsigned short f2h(float x) {
    __half h = __float2half(x);
    unsigned short u; __builtin_memcpy(&u, &h, 2); return u;
}
// broadcast low/high f16 of a u32 into both halves (one v_perm_b32)
__device__ __forceinline__ __half2 bcast_lo(unsigned u) {
    return u2h2(__builtin_amdgcn_perm(0u, u, 0x01000100u));
}
__device__ __forceinline__ __half2 bcast_hi(unsigned u) {
    return u2h2(__builtin_amdgcn_perm(0u, u, 0x03020302u));
}

// ---------------------------------------------------------------------------
// Kernel P (merged): blocks [0,1024) transpose concat(mem,que) -> xT f16,
// 128-px strip per block, float4-vectorized reads (r8 version used 32 scalar
// dword loads/thread -- Common-mistake #2); blocks [1024,1312) pack
// w_def/w_off into MFMA A-fragment order.
//   wpd: idx = (((g*9+k)*2+f)*64+L)*8+j  -> W[o=g*16+(L&15)][c=f*32+(L>>4)*8+j]
//   wpo: idx = (((ot*9+tap)*4+s)*64+L)*8+j -> o=ot*16+(L&15) (pad 27->32)
// ---------------------------------------------------------------------------
__global__ __launch_bounds__(256) void prep_kernel(
    const float* __restrict__ mem, const float* __restrict__ que,
    uint4* __restrict__ xT4,
    const float* __restrict__ w_def, const float* __restrict__ w_off,
    unsigned short* __restrict__ wpd, unsigned short* __restrict__ wpo)
{
    __shared__ unsigned tile[128 * 65];   // 33,280 B
    const int tid = threadIdx.x;

    if (blockIdx.x >= 1024) {
        int idx = (blockIdx.x - 1024) * 256 + tid;
        if (idx < CO_ * CM_ * Kn) {
            const int j  = idx & 7;
            const int L  = (idx >> 3) & 63;
            const int f  = (idx >> 9) & 1;
            const int gk = idx >> 10;
            const int k  = gk % 9;
            const int g  = gk / 9;
            const int o  = g * 16 + (L & 15);
            const int c  = f * 32 + (L >> 4) * 8 + j;
            wpd[idx] = f2h(w_def[(size_t)(o * CM_ + c) * Kn + k]);
            return;
        }
        idx -= CO_ * CM_ * Kn;
        if (idx < 2 * 9 * 4 * 64 * 8) {
            const int j   = idx & 7;
            const int L   = (idx >> 3) & 63;
            const int s   = (idx >> 9) & 3;
            const int r   = idx >> 11;
            const int tap = r % 9;
            const int ot  = r / 9;
            const int o   = ot * 16 + (L & 15);
            const int c   = s * 32 + (L >> 4) * 8 + j;
            wpo[idx] = (o < COFF) ? f2h(w_off[(size_t)(o * CIN + c) * Kn + tap])
                                  : (unsigned short)0;
        }
        return;
    }

    const int bb   = blockIdx.x & 7;            // batch -> XCD affinity
    const int pix0 = (blockIdx.x >> 3) * 128;   // 128-px strip

    const float* mb = mem + (size_t)bb * CM_ * HW + pix0;
    const float* qb = que + (size_t)bb * CM_ * HW + pix0;

    // stage: 2048 c-pair x px-quad units, 8 per thread, float4 reads
    #pragma unroll
    for (int i = 0; i < 8; ++i) {
        const int idx = i * 256 + tid;      // 0..2047
        const int cp  = idx >> 5;           // c-pair 0..63 (c0 = 2*cp even)
        const int sg  = idx & 31;           // px-quad 0..31
        const int c0  = cp * 2;
        const float4 a = (c0 < CM_)
            ? *(const float4*)(mb + (size_t)c0 * HW + sg * 4)
            : *(const float4*)(qb + (size_t)(c0 - CM_) * HW + sg * 4);
        const float4 b = (c0 + 1 < CM_)
            ? *(const float4*)(mb + (size_t)(c0 + 1) * HW + sg * 4)
            : *(const float4*)(qb + (size_t)(c0 + 1 - CM_) * HW + sg * 4);
        tile[(sg * 4 + 0) * 65 + cp] = h22u(__floats2half2_rn(a.x, b.x));
        tile[(sg * 4 + 1) * 65 + cp] = h22u(__floats2half2_rn(a.y, b.y));
        tile[(sg * 4 + 2) * 65 + cp] = h22u(__floats2half2_rn(a.z, b.z));
        tile[(sg * 4 + 3) * 65 + cp] = h22u(__floats2half2_rn(a.w, b.w));
    }
    __syncthreads();

    uint4* dst = xT4 + (size_t)(bb * HW + pix0) * 16;
    #pragma unroll
    for (int p = 0; p < 8; ++p) {
        const int G  = p * 256 + tid;   // 0..2047
        const int px = G >> 4;
        const int u  = G & 15;
        uint4 v;
        v.x = tile[px * 65 + u * 4 + 0];
        v.y = tile[px * 65 + u * 4 + 1];
        v.z = tile[px * 65 + u * 4 + 2];
        v.w = tile[px * 65 + u * 4 + 3];
        dst[G] = v;
    }
}

// ---------------------------------------------------------------------------
// Fused kernel: byte-identical to round 8 (verified best, 56.4 us).
// LDS map (25,600 B):
//   [0, 25,344)      xw (phase 1 only; dead after final phase-1 barrier)
//   [0, 16,384)      smp4 (phase 2) / offl 27*64 f32 [0,6912) (ph1->1.5 only)
//   [16,384, 25,600) tab 9*64 uint4 (phase 1.5 write, phase 2 read)
// ---------------------------------------------------------------------------
__global__ __launch_bounds__(256) void fused_deform_kernel(
    const uint4* __restrict__ xT4, const uint4* __restrict__ wpo,
    const uint4* __restrict__ wpd, const float* __restrict__ b_off,
    float* __restrict__ out)
{
    __shared__ __align__(16) char lds[25600];
    uint4* xw   = (uint4*)lds;
    uint4* smp4 = (uint4*)lds;                          // 16,384 B
    float* offl = (float*)lds;                          // 6,912 B (transient)
    uint4* tab  = (uint4*)(lds + 16384);                // 9,216 B

    const int bb   = blockIdx.x & 7;                    // batch -> XCD affinity
    const int pix0 = (blockIdx.x >> 3) * 64;
    const int h0   = pix0 >> 7;
    const int w0   = pix0 & 127;
    const int tid  = threadIdx.x;
    const int wv   = tid >> 6;
    const int lane = tid & 63;
    const int quad = lane >> 4;
    const int lrow = lane & 15;

    const uint4* xb = xT4 + (size_t)bb * HW * 16;

    // ======== phase 1: offset-conv GEMM, two 64-channel halves ========
    {
        const int ot   = wv >> 1;
        const int sub0 = (wv & 1) * 2;

        f32x4 oacc[2];
        #pragma unroll
        for (int t = 0; t < 2; ++t)
            #pragma unroll
            for (int r = 0; r < 4; ++r) {
                const int o = ot * 16 + quad * 4 + r;
                oacc[t][r] = (o < COFF) ? b_off[o] : 0.0f;
            }

        #pragma unroll
        for (int Hh = 0; Hh < 2; ++Hh) {
            // ---- stage 3x66 window, 64-channel half Hh ----
            #pragma unroll
            for (int g = 0; g < 7; ++g) {
                const int idx = g * 256 + tid;
                if (idx < 198 * 8) {
                    const int slot = idx >> 3;
                    const int j    = idx & 7;
                    const int r    = slot / 66;
                    const int c    = slot - r * 66;
                    const int y    = h0 + r - 1;
                    const int x    = w0 + c - 1;
                    const bool ok  = (y >= 0) & (y < Hn) & (x >= 0) & (x < Wn);
                    uint4 v = make_uint4(0, 0, 0, 0);
                    if (ok) v = xb[(size_t)(y * Wn + x) * 16 + Hh * 8 + j];
                    xw[slot * 8 + (j ^ (slot & 7))] = v;
                }
            }
            __syncthreads();

            #pragma unroll
            for (int tap = 0; tap < 9; ++tap) {
                const int rr = tap / 3;
                const int cc = tap % 3;

                const uint4* ap = wpo
                    + (size_t)((ot * 9 + tap) * 4 + Hh * 2) * 64 + lane;
                f16x8 a[2];
                #pragma unroll
                for (int s = 0; s < 2; ++s)
                    a[s] = __builtin_bit_cast(f16x8, ap[s * 64]);

                #pragma unroll
                for (int t = 0; t < 2; ++t) {
                    const int pl   = (sub0 + t) * 16 + lrow;
                    const int slot = rr * 66 + pl + cc;
                    const int base = slot * 8;
                    const int sw   = slot & 7;
                    #pragma unroll
                    for (int s = 0; s < 2; ++s) {
                        const f16x8 bfrag = __builtin_bit_cast(f16x8,
                            xw[base + ((s * 4 + quad) ^ sw)]);
                        oacc[t] = __builtin_amdgcn_mfma_f32_16x16x32_f16(
                            a[s], bfrag, oacc[t], 0, 0, 0);
                    }
                }
            }
            __syncthreads();   // Hh=0: before restage; Hh=1: xw reads done
                               //   before offl overlays xw bytes [0,6912)
        }

        #pragma unroll
        for (int t = 0; t < 2; ++t) {
            const int pl = (sub0 + t) * 16 + lrow;
            #pragma unroll
            for (int r = 0; r < 4; ++r) {
                const int o = ot * 16 + quad * 4 + r;
                if (o < COFF) offl[o * 64 + pl] = oacc[t][r];
            }
        }
        __syncthreads();   // offl visible to all
    }

    // ======== phase 1.5: build per-(px,tap) sample table (once) ========
    // tab[e] = { i00|i01<<16, i10|i11<<16, h00|h01<<16, h10|h11<<16 }
    for (int e = tid; e < 9 * 64; e += 256) {
        const int k  = e >> 6;          // tap 0..8
        const int pl = e & 63;
        const int pG = pix0 + pl;
        const float dy = offl[(2 * k    ) * 64 + pl];
        const float dx = offl[(2 * k + 1) * 64 + pl];
        const float mk = offl[(18 + k   ) * 64 + pl];
        const float py  = (float)((pG >> 7)  + k / 3 - 1) + dy;
        const float pxf = (float)((pG & 127) + k % 3 - 1) + dx;
        const float y0f = floorf(py), x0f = floorf(pxf);
        const float fy = py - y0f,  fx = pxf - x0f;
        const int y0 = (int)y0f, x0 = (int)x0f;
        const int y1 = y0 + 1,   x1 = x0 + 1;
        const bool vy0 = (y0 >= 0) & (y0 < Hn);
        const bool vy1 = (y1 >= 0) & (y1 < Hn);
        const bool vx0 = (x0 >= 0) & (x0 < Wn);
        const bool vx1 = (x1 >= 0) & (x1 < Wn);
        const float w00 = (1.f - fy) * (1.f - fx) * (float)(vy0 & vx0) * mk;
        const float w01 = (1.f - fy) * fx         * (float)(vy0 & vx1) * mk;
        const float w10 = fy * (1.f - fx)         * (float)(vy1 & vx0) * mk;
        const float w11 = fy * fx                 * (float)(vy1 & vx1) * mk;
        const int y0c = min(max(y0, 0), Hn - 1);
        const int y1c = min(max(y1, 0), Hn - 1);
        const int x0c = min(max(x0, 0), Wn - 1);
        const int x1c = min(max(x1, 0), Wn - 1);
        const unsigned i00 = (unsigned)(y0c * Wn + x0c);
        const unsigned i01 = (unsigned)(y0c * Wn + x1c);
        const unsigned i10 = (unsigned)(y1c * Wn + x0c);
        const unsigned i11 = (unsigned)(y1c * Wn + x1c);
        tab[e] = make_uint4(i00 | (i01 << 16), i10 | (i11 << 16),
                            (unsigned)f2h(w00) | ((unsigned)f2h(w01) << 16),
                            (unsigned)f2h(w10) | ((unsigned)f2h(w11) << 16));
    }
    __syncthreads();   // table visible; offl and xw now dead

    // ======== phase 2: deformable sampling + deform GEMM, depth-2 ========
    const int chunk = lane & 7;
    const int psub  = lane >> 3;

    int plg[2];
    #pragma unroll
    for (int g = 0; g < 2; ++g) plg[g] = g * 32 + wv * 8 + psub;

    f32x4 acc[4];
    #pragma unroll
    for (int i = 0; i < 4; ++i) acc[i] = (f32x4){0.f, 0.f, 0.f, 0.f};

    uint4   GB[2][8];        // [tap parity][corner*2 + g]
    __half2 WB[2][2][4];     // [tap parity][g][corner]
    f16x8   AF[2][2];        // [tap parity][k-half]

    auto prep_issue = [&](int k) {
        const int par = k & 1;
        #pragma unroll
        for (int g = 0; g < 2; ++g) {
            const int pl = plg[g];
            const uint4 tv = tab[k * 64 + pl];      // 1 broadcast ds_read_b128
            WB[par][g][0] = bcast_lo(tv.z);
            WB[par][g][1] = bcast_hi(tv.z);
            WB[par][g][2] = bcast_lo(tv.w);
            WB[par][g][3] = bcast_hi(tv.w);
            const int i00 = (int)(tv.x & 0xFFFFu);
            const int i01 = (int)(tv.x >> 16);
            const int i10 = (int)(tv.y & 0xFFFFu);
            const int i11 = (int)(tv.y >> 16);
            GB[par][0 + g] = xb[(size_t)i00 * 16 + chunk];
            GB[par][2 + g] = xb[(size_t)i01 * 16 + chunk];
            GB[par][4 + g] = xb[(size_t)i10 * 16 + chunk];
            GB[par][6 + g] = xb[(size_t)i11 * 16 + chunk];
        }
    };

    auto blend_store = [&](int k) {
        const int par = k & 1;
        #pragma unroll
        for (int g = 0; g < 2; ++g) {
            const int pl = plg[g];
            const uint4 g00 = GB[par][0 + g], g01 = GB[par][2 + g];
            const uint4 g10 = GB[par][4 + g], g11 = GB[par][6 + g];
            const unsigned u00[4] = {g00.x, g00.y, g00.z, g00.w};
            const unsigned u01[4] = {g01.x, g01.y, g01.z, g01.w};
            const unsigned u10[4] = {g10.x, g10.y, g10.z, g10.w};
            const unsigned u11[4] = {g11.x, g11.y, g11.z, g11.w};
            unsigned pk[4];
            #pragma unroll
            for (int d = 0; d < 4; ++d) {
                __half2 s = __hmul2(u2h2(u00[d]), WB[par][g][0]);
                s = __hfma2(u2h2(u01[d]), WB[par][g][1], s);
                s = __hfma2(u2h2(u10[d]), WB[par][g][2], s);
                s = __hfma2(u2h2(u11[d]), WB[par][g][3], s);
                pk[d] = h22u(s);
            }
            smp4[par * 512 + pl * 8 + (chunk ^ (pl & 7))] =
                make_uint4(pk[0], pk[1], pk[2], pk[3]);
        }
    };

    auto load_af = [&](int k) {
        const uint4* wpk = wpd + (size_t)((wv * 9 + k) * 2) * 64 + lane;
        AF[k & 1][0] = __builtin_bit_cast(f16x8, wpk[0]);
        AF[k & 1][1] = __builtin_bit_cast(f16x8, wpk[64]);
    };

    // preamble: fill the 2-deep pipe
    prep_issue(0);
    prep_issue(1);
    load_af(0);
    blend_store(0);          // waits only tap-0 gathers
    __syncthreads();

    #pragma unroll
    for (int t = 0; t < Kn; ++t) {
        if (t + 1 < Kn) load_af(t + 1);       // A-frags for next tap
        if (t + 2 < Kn) prep_issue(t + 2);    // gathers fly for 2 taps

        const int buf = t & 1;
        #pragma unroll
        for (int nt = 0; nt < 4; ++nt) {
            const int pm = nt * 16 + lrow;
            const f16x8 b0 = __builtin_bit_cast(f16x8,
                smp4[buf * 512 + pm * 8 + ( quad      ^ (pm & 7))]);
            const f16x8 b1 = __builtin_bit_cast(f16x8,
                smp4[buf * 512 + pm * 8 + ((quad + 4) ^ (pm & 7))]);
            acc[nt] = __builtin_amdgcn_mfma_f32_16x16x32_f16(AF[buf][0], b0, acc[nt], 0, 0, 0);
            acc[nt] = __builtin_amdgcn_mfma_f32_16x16x32_f16(AF[buf][1], b1, acc[nt], 0, 0, 0);
        }

        if (t + 1 < Kn) {
            blend_store(t + 1);   // waits tap t+1 gathers; t+2 stay in flight
            __syncthreads();
        }
    }

    const int obase = (wv << 4) + (quad << 2);
    #pragma unroll
    for (int nt = 0; nt < 4; ++nt) {
        const int pp = pix0 + nt * 16 + lrow;
        #pragma unroll
        for (int r = 0; r < 4; ++r)
            out[(size_t)(bb * CO_ + obase + r) * HW + pp] = acc[nt][r];
    }
}

extern "C" void kernel_launch(void* const* d_in, const int* in_sizes, int n_in,
                              void* d_out, int out_size, void* d_ws, size_t ws_size,
                              hipStream_t stream) {
    const float* mem   = (const float*)d_in[0];
    const float* que   = (const float*)d_in[1];
    const float* w_off = (const float*)d_in[2];
    const float* b_off = (const float*)d_in[3];
    const float* w_def = (const float*)d_in[4];
    float* out = (float*)d_out;

    char* ws = (char*)d_ws;
    unsigned short* wpd = (unsigned short*)ws;             //  73,728 B
    unsigned short* wpo = (unsigned short*)(ws + 73728);   //  73,728 B
    uint4*          xT4 = (uint4*)(ws + 147456);           //  33,554,432 B

    prep_kernel<<<1312, 256, 0, stream>>>(mem, que, xT4, w_def, w_off, wpd, wpo);
    fused_deform_kernel<<<2048, 256, 0, stream>>>(
        xT4, (const uint4*)wpo, (const uint4*)wpd, b_off, out);
}